// Round 3
// baseline (184.128 us; speedup 1.0000x reference)
//
#include <hip/hip_runtime.h>

#ifndef ALPHA_F
#define ALPHA_F 0.25f
#define DELTA_F 0.5f
#endif

// Per-element losses, fused single pass over all 4 inputs.
// Grid-stride, float4 vectorized (16B/lane/array), fp64 accumulation.
__global__ __launch_bounds__(256) void loss_main_kernel(
    const float* __restrict__ bp_s, const float* __restrict__ bt_s,
    const float* __restrict__ sp_s, const float* __restrict__ st_s,
    double* __restrict__ acc, int n)
{
    const int n4 = n >> 2;                 // number of float4 chunks
    const int rem = n - (n4 << 2);         // scalar tail (0 for this problem)
    const float4* __restrict__ bp = (const float4*)bp_s;
    const float4* __restrict__ bt = (const float4*)bt_s;
    const float4* __restrict__ sp = (const float4*)sp_s;
    const float4* __restrict__ st = (const float4*)st_s;

    double abce = 0.0, adur = 0.0;
    const int stride = gridDim.x * blockDim.x;
    for (int i = blockIdx.x * blockDim.x + threadIdx.x; i < n4; i += stride) {
        float4 p4 = bp[i], t4 = bt[i], yp4 = sp[i], yt4 = st[i];
        float ps[4]  = {p4.x,  p4.y,  p4.z,  p4.w};
        float ts[4]  = {t4.x,  t4.y,  t4.z,  t4.w};
        float yps[4] = {yp4.x, yp4.y, yp4.z, yp4.w};
        float yts[4] = {yt4.x, yt4.y, yt4.z, yt4.w};
        float bsum = 0.f, dsum = 0.f;
        #pragma unroll
        for (int j = 0; j < 4; ++j) {
            // ---- BCE term ----
            float p = fminf(fmaxf(ps[j], 0.f), 1.f);
            float t = fminf(fmaxf(ts[j], 0.f), 1.f);
            float logp   = fmaxf(logf(p),    -100.f);   // clip(log p, -100, ·)
            float log1mp = fmaxf(log1pf(-p), -100.f);   // clip(log1p(-p), -100, ·)
            bsum += -(t * logp + (1.f - t) * log1mp);
            // ---- duration focal term ----
            float yp = yps[j], yt = yts[j];
            float d = fabsf(yp - yt);
            float r = fminf(d * (1.f / DELTA_F), 1.f);  // clip(d/DELTA,0,1); d>=0
            float focal = r * r;                         // ^GAMMA (=2)
            float base = (d < DELTA_F) ? (d * d)         // 0.5*d*d/0.5
                                       : (d - 0.5f * DELTA_F);
            int cls = (int)fminf(fmaxf(rintf(yt), 0.f), 3.f);  // round half-even like jnp.round
            float w = (cls == 1) ? 4.f : (cls == 2) ? 3.f : (cls == 3) ? 2.f : 1.f;
            dsum += ALPHA_F * focal * base * w;
        }
        abce += (double)bsum;
        adur += (double)dsum;
    }

    // scalar tail (defensive; n is divisible by 4 here)
    if (rem && blockIdx.x == 0 && threadIdx.x == 0) {
        for (int i = n4 << 2; i < n; ++i) {
            float p = fminf(fmaxf(bp_s[i], 0.f), 1.f);
            float t = fminf(fmaxf(bt_s[i], 0.f), 1.f);
            float logp   = fmaxf(logf(p),    -100.f);
            float log1mp = fmaxf(log1pf(-p), -100.f);
            abce += (double)(-(t * logp + (1.f - t) * log1mp));
            float yp = sp_s[i], yt = st_s[i];
            float d = fabsf(yp - yt);
            float r = fminf(d * (1.f / DELTA_F), 1.f);
            float base = (d < DELTA_F) ? (d * d) : (d - 0.5f * DELTA_F);
            int cls = (int)fminf(fmaxf(rintf(yt), 0.f), 3.f);
            float w = (cls == 1) ? 4.f : (cls == 2) ? 3.f : (cls == 3) ? 2.f : 1.f;
            adur += (double)(ALPHA_F * r * r * base * w);
        }
    }

    // 64-lane wave reduction (wave = 64 on CDNA)
    for (int off = 32; off > 0; off >>= 1) {
        abce += __shfl_down(abce, off);
        adur += __shfl_down(adur, off);
    }
    __shared__ double sb[4], sd[4];
    const int lane = threadIdx.x & 63;
    const int wid  = threadIdx.x >> 6;
    if (lane == 0) { sb[wid] = abce; sd[wid] = adur; }
    __syncthreads();
    if (threadIdx.x == 0) {
        double tb = sb[0] + sb[1] + sb[2] + sb[3];
        double td = sd[0] + sd[1] + sd[2] + sd[3];
        atomicAdd(&acc[0], tb);   // device-scope by default (G12)
        atomicAdd(&acc[1], td);
    }
}

__global__ void loss_finalize_kernel(const double* __restrict__ acc,
                                     float* __restrict__ out, double invn)
{
    double bce = acc[0] * invn;
    double dur = acc[1] * invn;
    out[0] = (float)(bce + dur);   // BREAK_W = DUR_W = 1.0
    out[1] = (float)bce;
    out[2] = (float)dur;
}

extern "C" void kernel_launch(void* const* d_in, const int* in_sizes, int n_in,
                              void* d_out, int out_size, void* d_ws, size_t ws_size,
                              hipStream_t stream)
{
    const float* bp = (const float*)d_in[0];
    const float* bt = (const float*)d_in[1];
    const float* sp = (const float*)d_in[2];
    const float* st = (const float*)d_in[3];
    float* out = (float*)d_out;
    double* acc = (double*)d_ws;

    const int n = in_sizes[0];   // 64 * 131072 = 8,388,608

    // ws is re-poisoned to 0xAA before every timed launch — must zero each call.
    hipMemsetAsync(acc, 0, 2 * sizeof(double), stream);

    const int block = 256;
    const int grid  = 2048;      // ~8 blocks/CU worth of waves; grid-stride covers rest
    loss_main_kernel<<<grid, block, 0, stream>>>(bp, bt, sp, st, acc, n);
    loss_finalize_kernel<<<1, 1, 0, stream>>>(acc, out, 1.0 / (double)n);
}

// Round 4
// 175.627 us; speedup vs baseline: 1.0484x; 1.0484x over previous
//
#include <hip/hip_runtime.h>

// Constants factored out of the per-element math:
//   BCE is computed in log2 domain; multiply by -ln2 in finalize.
//   Focal ALPHA=0.25 applied in finalize.
#define LOG2_CLAMP (-144.26950408889634f)   /* -100 / ln(2) */
#define NEG_LN2    (-0.6931471805599453)
#define ALPHA_D    (0.25)

__device__ __forceinline__ void loss_elem(float pr, float tr, float yp, float yt,
                                          float& bsum, float& dsum)
{
    // ---- BCE (log2 domain, scale by -ln2 deferred) ----
    float p = fminf(fmaxf(pr, 0.f), 1.f);
    float t = fminf(fmaxf(tr, 0.f), 1.f);
    // v_log_f32: p=0 -> -inf, fmaxf(-inf, clamp) = clamp  (matches clip(log,-100))
    float l2p = fmaxf(__log2f(p),       LOG2_CLAMP);
    float l2q = fmaxf(__log2f(1.f - p), LOG2_CLAMP);
    bsum += t * (l2p - l2q) + l2q;          // * -ln2 at finalize
    // ---- duration focal (ALPHA deferred) ----
    float d = fabsf(yp - yt);
    float r = fminf(d + d, 1.f);            // clip(d/0.5, 0, 1)
    float base = (d < 0.5f) ? (d * d)       // 0.5*d*d/0.5
                            : (d - 0.25f);  // d - 0.5*DELTA
    float c = fminf(fmaxf(rintf(yt), 0.f), 3.f);   // round half-even, clamp [0,3]
    float w = (c == 0.f) ? 1.f : (5.f - c);        // {0,1,2,3} -> {1,4,3,2}
    dsum += ((r * r) * base) * w;
}

// Fused single pass over all 4 inputs. 2-chunk batches: 8 independent
// global_load_dwordx4 in flight per thread (128 B/lane), VGPR kept <=64
// so we retain 8 waves/SIMD.
__global__ __launch_bounds__(256) void loss_main_kernel(
    const float* __restrict__ bp_s, const float* __restrict__ bt_s,
    const float* __restrict__ sp_s, const float* __restrict__ st_s,
    double* __restrict__ acc, int n)
{
    const int n4 = n >> 2;
    const float4* __restrict__ bp = (const float4*)bp_s;
    const float4* __restrict__ bt = (const float4*)bt_s;
    const float4* __restrict__ sp = (const float4*)sp_s;
    const float4* __restrict__ st = (const float4*)st_s;

    const int stride = gridDim.x * blockDim.x;
    int i = blockIdx.x * blockDim.x + threadIdx.x;

    double abce = 0.0, adur = 0.0;

    // main: two float4 chunks per iteration -> 8 loads issued before consumption
    for (; i + stride < n4; i += 2 * stride) {
        float4 P0 = bp[i],          T0 = bt[i],          Y0 = sp[i],          Z0 = st[i];
        float4 P1 = bp[i + stride], T1 = bt[i + stride], Y1 = sp[i + stride], Z1 = st[i + stride];
        float bsum = 0.f, dsum = 0.f;
        loss_elem(P0.x, T0.x, Y0.x, Z0.x, bsum, dsum);
        loss_elem(P0.y, T0.y, Y0.y, Z0.y, bsum, dsum);
        loss_elem(P0.z, T0.z, Y0.z, Z0.z, bsum, dsum);
        loss_elem(P0.w, T0.w, Y0.w, Z0.w, bsum, dsum);
        loss_elem(P1.x, T1.x, Y1.x, Z1.x, bsum, dsum);
        loss_elem(P1.y, T1.y, Y1.y, Z1.y, bsum, dsum);
        loss_elem(P1.z, T1.z, Y1.z, Z1.z, bsum, dsum);
        loss_elem(P1.w, T1.w, Y1.w, Z1.w, bsum, dsum);
        abce += (double)bsum;
        adur += (double)dsum;
    }
    // leftover single chunk (grid-stride remainder)
    for (; i < n4; i += stride) {
        float4 P0 = bp[i], T0 = bt[i], Y0 = sp[i], Z0 = st[i];
        float bsum = 0.f, dsum = 0.f;
        loss_elem(P0.x, T0.x, Y0.x, Z0.x, bsum, dsum);
        loss_elem(P0.y, T0.y, Y0.y, Z0.y, bsum, dsum);
        loss_elem(P0.z, T0.z, Y0.z, Z0.z, bsum, dsum);
        loss_elem(P0.w, T0.w, Y0.w, Z0.w, bsum, dsum);
        abce += (double)bsum;
        adur += (double)dsum;
    }
    // scalar tail (n % 4 != 0 — defensive; zero here)
    const int rem = n - (n4 << 2);
    if (rem && blockIdx.x == 0 && threadIdx.x == 0) {
        float bsum = 0.f, dsum = 0.f;
        for (int k = n4 << 2; k < n; ++k)
            loss_elem(bp_s[k], bt_s[k], sp_s[k], st_s[k], bsum, dsum);
        abce += (double)bsum;
        adur += (double)dsum;
    }

    // 64-lane wave reduction
    for (int off = 32; off > 0; off >>= 1) {
        abce += __shfl_down(abce, off);
        adur += __shfl_down(adur, off);
    }
    __shared__ double sb[4], sd[4];
    const int lane = threadIdx.x & 63;
    const int wid  = threadIdx.x >> 6;
    if (lane == 0) { sb[wid] = abce; sd[wid] = adur; }
    __syncthreads();
    if (threadIdx.x == 0) {
        atomicAdd(&acc[0], sb[0] + sb[1] + sb[2] + sb[3]);
        atomicAdd(&acc[1], sd[0] + sd[1] + sd[2] + sd[3]);
    }
}

__global__ void loss_finalize_kernel(const double* __restrict__ acc,
                                     float* __restrict__ out, double invn)
{
    double bce = acc[0] * NEG_LN2 * invn;   // undo log2 domain
    double dur = acc[1] * ALPHA_D * invn;   // apply focal alpha
    out[0] = (float)(bce + dur);
    out[1] = (float)bce;
    out[2] = (float)dur;
}

extern "C" void kernel_launch(void* const* d_in, const int* in_sizes, int n_in,
                              void* d_out, int out_size, void* d_ws, size_t ws_size,
                              hipStream_t stream)
{
    const float* bp = (const float*)d_in[0];
    const float* bt = (const float*)d_in[1];
    const float* sp = (const float*)d_in[2];
    const float* st = (const float*)d_in[3];
    float* out = (float*)d_out;
    double* acc = (double*)d_ws;

    const int n = in_sizes[0];   // 64 * 131072 = 8,388,608

    // ws is re-poisoned to 0xAA before every timed launch — zero each call.
    hipMemsetAsync(acc, 0, 2 * sizeof(double), stream);

    const int block = 256;
    const int grid  = 2048;      // 8 blocks/CU; each thread handles 4 float4 chunks
    loss_main_kernel<<<grid, block, 0, stream>>>(bp, bt, sp, st, acc, n);
    loss_finalize_kernel<<<1, 64, 0, stream>>>(acc, out, 1.0 / (double)n);
}

// Round 7
// 150.487 us; speedup vs baseline: 1.2235x; 1.1671x over previous
//
#include <hip/hip_runtime.h>

// BCE computed in log2 domain; -ln2 applied at finalize. Focal ALPHA deferred too.
#define LOG2_CLAMP (-144.26950408889634f)   /* -100 / ln(2) */
#define NEG_LN2    (-0.6931471805599453)
#define ALPHA_D    (0.25)
#define NBLOCKS    2048

__device__ __forceinline__ void loss_elem(float pr, float tr, float yp, float yt,
                                          float& bsum, float& dsum)
{
    // ---- BCE (log2 domain) ----
    float p = fminf(fmaxf(pr, 0.f), 1.f);
    float t = fminf(fmaxf(tr, 0.f), 1.f);
    float l2p = fmaxf(__log2f(p),       LOG2_CLAMP);   // p=0 -> -inf -> clamp
    float l2q = fmaxf(__log2f(1.f - p), LOG2_CLAMP);
    bsum += t * (l2p - l2q) + l2q;          // * -ln2 at finalize
    // ---- duration focal (ALPHA deferred) ----
    float d = fabsf(yp - yt);
    float r = fminf(d + d, 1.f);            // clip(d/0.5, 0, 1)
    float base = (d < 0.5f) ? (d * d)       // 0.5*d*d/0.5
                            : (d - 0.25f);  // d - 0.5*DELTA
    float c = fminf(fmaxf(rintf(yt), 0.f), 3.f);   // round half-even, clamp [0,3]
    float w = (c == 0.f) ? 1.f : (5.f - c);        // {0,1,2,3} -> {1,4,3,2}
    dsum += ((r * r) * base) * w;
}

// Pass 1: fused streaming; per-block partial pair stored to ws (NO atomics —
// R4 counters showed a serialized same-line atomic tail: occupancy 43%,
// VALU 9%, HBM 13%).
__global__ __launch_bounds__(256) void loss_main_kernel(
    const float* __restrict__ bp_s, const float* __restrict__ bt_s,
    const float* __restrict__ sp_s, const float* __restrict__ st_s,
    double2* __restrict__ partials, int n)
{
    const int n4 = n >> 2;
    const float4* __restrict__ bp = (const float4*)bp_s;
    const float4* __restrict__ bt = (const float4*)bt_s;
    const float4* __restrict__ sp = (const float4*)sp_s;
    const float4* __restrict__ st = (const float4*)st_s;

    const int stride = gridDim.x * blockDim.x;
    int i = blockIdx.x * blockDim.x + threadIdx.x;

    double abce = 0.0, adur = 0.0;

    // two float4 chunks per iteration -> 8 independent dwordx4 loads in flight
    for (; i + stride < n4; i += 2 * stride) {
        float4 P0 = bp[i],          T0 = bt[i],          Y0 = sp[i],          Z0 = st[i];
        float4 P1 = bp[i + stride], T1 = bt[i + stride], Y1 = sp[i + stride], Z1 = st[i + stride];
        float bsum = 0.f, dsum = 0.f;
        loss_elem(P0.x, T0.x, Y0.x, Z0.x, bsum, dsum);
        loss_elem(P0.y, T0.y, Y0.y, Z0.y, bsum, dsum);
        loss_elem(P0.z, T0.z, Y0.z, Z0.z, bsum, dsum);
        loss_elem(P0.w, T0.w, Y0.w, Z0.w, bsum, dsum);
        loss_elem(P1.x, T1.x, Y1.x, Z1.x, bsum, dsum);
        loss_elem(P1.y, T1.y, Y1.y, Z1.y, bsum, dsum);
        loss_elem(P1.z, T1.z, Y1.z, Z1.z, bsum, dsum);
        loss_elem(P1.w, T1.w, Y1.w, Z1.w, bsum, dsum);
        abce += (double)bsum;
        adur += (double)dsum;
    }
    for (; i < n4; i += stride) {
        float4 P0 = bp[i], T0 = bt[i], Y0 = sp[i], Z0 = st[i];
        float bsum = 0.f, dsum = 0.f;
        loss_elem(P0.x, T0.x, Y0.x, Z0.x, bsum, dsum);
        loss_elem(P0.y, T0.y, Y0.y, Z0.y, bsum, dsum);
        loss_elem(P0.z, T0.z, Y0.z, Z0.z, bsum, dsum);
        loss_elem(P0.w, T0.w, Y0.w, Z0.w, bsum, dsum);
        abce += (double)bsum;
        adur += (double)dsum;
    }
    const int rem = n - (n4 << 2);   // defensive; zero for this shape
    if (rem && blockIdx.x == 0 && threadIdx.x == 0) {
        float bsum = 0.f, dsum = 0.f;
        for (int k = n4 << 2; k < n; ++k)
            loss_elem(bp_s[k], bt_s[k], sp_s[k], st_s[k], bsum, dsum);
        abce += (double)bsum;
        adur += (double)dsum;
    }

    // wave reduce (64 lanes)
    for (int off = 32; off > 0; off >>= 1) {
        abce += __shfl_down(abce, off);
        adur += __shfl_down(adur, off);
    }
    __shared__ double sb[4], sd[4];
    const int lane = threadIdx.x & 63;
    const int wid  = threadIdx.x >> 6;
    if (lane == 0) { sb[wid] = abce; sd[wid] = adur; }
    __syncthreads();
    if (threadIdx.x == 0)
        partials[blockIdx.x] = make_double2(sb[0] + sb[1] + sb[2] + sb[3],
                                            sd[0] + sd[1] + sd[2] + sd[3]);
}

// Pass 2: one block reduces NBLOCKS partial pairs, writes the 3 outputs.
__global__ __launch_bounds__(256) void loss_finalize_kernel(
    const double2* __restrict__ partials, float* __restrict__ out, double invn)
{
    double abce = 0.0, adur = 0.0;
    for (int i = threadIdx.x; i < NBLOCKS; i += 256) {
        double2 v = partials[i];
        abce += v.x;
        adur += v.y;
    }
    for (int off = 32; off > 0; off >>= 1) {
        abce += __shfl_down(abce, off);
        adur += __shfl_down(adur, off);
    }
    __shared__ double sb[4], sd[4];
    const int lane = threadIdx.x & 63;
    const int wid  = threadIdx.x >> 6;
    if (lane == 0) { sb[wid] = abce; sd[wid] = adur; }
    __syncthreads();
    if (threadIdx.x == 0) {
        double bce = (sb[0] + sb[1] + sb[2] + sb[3]) * NEG_LN2 * invn;
        double dur = (sd[0] + sd[1] + sd[2] + sd[3]) * ALPHA_D * invn;
        out[0] = (float)(bce + dur);
        out[1] = (float)bce;
        out[2] = (float)dur;
    }
}

extern "C" void kernel_launch(void* const* d_in, const int* in_sizes, int n_in,
                              void* d_out, int out_size, void* d_ws, size_t ws_size,
                              hipStream_t stream)
{
    const float* bp = (const float*)d_in[0];
    const float* bt = (const float*)d_in[1];
    const float* sp = (const float*)d_in[2];
    const float* st = (const float*)d_in[3];
    float* out = (float*)d_out;
    double2* partials = (double2*)d_ws;     // NBLOCKS * 16 B = 32 KB scratch

    const int n = in_sizes[0];   // 64 * 131072 = 8,388,608

    // No memset needed: every partial slot is unconditionally overwritten.
    loss_main_kernel<<<NBLOCKS, 256, 0, stream>>>(bp, bt, sp, st, partials, n);
    loss_finalize_kernel<<<1, 256, 0, stream>>>(partials, out, 1.0 / (double)n);
}

// Round 10
// 149.220 us; speedup vs baseline: 1.2339x; 1.0085x over previous
//
#include <hip/hip_runtime.h>

// BCE computed in log2 domain; -ln2 applied at finalize. Focal ALPHA deferred too.
#define LOG2_CLAMP (-144.26950408889634f)   /* -100 / ln(2) */
#define NEG_LN2    (-0.6931471805599453)
#define ALPHA_D    (0.25)
#define NBLOCKS    1024   /* R7 proved this structure at 2048; halving doubles per-thread
                             iterations (2->4) to build a steady state (R7: occ 45%,
                             VALU 13%, HBM 19% => latency/ramp-bound burst pattern). */

__device__ __forceinline__ void loss_elem(float pr, float tr, float yp, float yt,
                                          float& bsum, float& dsum)
{
    // ---- BCE (log2 domain) ----
    float p = fminf(fmaxf(pr, 0.f), 1.f);
    float t = fminf(fmaxf(tr, 0.f), 1.f);
    float l2p = fmaxf(__log2f(p),       LOG2_CLAMP);   // p=0 -> -inf -> clamp
    float l2q = fmaxf(__log2f(1.f - p), LOG2_CLAMP);
    bsum += t * (l2p - l2q) + l2q;          // * -ln2 at finalize
    // ---- duration focal (ALPHA deferred) ----
    float d = fabsf(yp - yt);
    float r = fminf(d + d, 1.f);            // clip(d/0.5, 0, 1)
    float base = (d < 0.5f) ? (d * d)       // 0.5*d*d/0.5
                            : (d - 0.25f);  // d - 0.5*DELTA
    float c = fminf(fmaxf(rintf(yt), 0.f), 3.f);   // round half-even, clamp [0,3]
    float w = (c == 0.f) ? 1.f : (5.f - c);        // {0,1,2,3} -> {1,4,3,2}
    dsum += ((r * r) * base) * w;
}

// Pass 1: fused streaming; per-block partial pair stored to ws (no atomics).
__global__ __launch_bounds__(256) void loss_main_kernel(
    const float* __restrict__ bp_s, const float* __restrict__ bt_s,
    const float* __restrict__ sp_s, const float* __restrict__ st_s,
    double2* __restrict__ partials, int n)
{
    const int n4 = n >> 2;
    const float4* __restrict__ bp = (const float4*)bp_s;
    const float4* __restrict__ bt = (const float4*)bt_s;
    const float4* __restrict__ sp = (const float4*)sp_s;
    const float4* __restrict__ st = (const float4*)st_s;

    const int stride = gridDim.x * blockDim.x;
    int i = blockIdx.x * blockDim.x + threadIdx.x;

    double abce = 0.0, adur = 0.0;

    // two float4 chunks per iteration -> 8 independent dwordx4 loads in flight
    for (; i + stride < n4; i += 2 * stride) {
        float4 P0 = bp[i],          T0 = bt[i],          Y0 = sp[i],          Z0 = st[i];
        float4 P1 = bp[i + stride], T1 = bt[i + stride], Y1 = sp[i + stride], Z1 = st[i + stride];
        float bsum = 0.f, dsum = 0.f;
        loss_elem(P0.x, T0.x, Y0.x, Z0.x, bsum, dsum);
        loss_elem(P0.y, T0.y, Y0.y, Z0.y, bsum, dsum);
        loss_elem(P0.z, T0.z, Y0.z, Z0.z, bsum, dsum);
        loss_elem(P0.w, T0.w, Y0.w, Z0.w, bsum, dsum);
        loss_elem(P1.x, T1.x, Y1.x, Z1.x, bsum, dsum);
        loss_elem(P1.y, T1.y, Y1.y, Z1.y, bsum, dsum);
        loss_elem(P1.z, T1.z, Y1.z, Z1.z, bsum, dsum);
        loss_elem(P1.w, T1.w, Y1.w, Z1.w, bsum, dsum);
        abce += (double)bsum;
        adur += (double)dsum;
    }
    for (; i < n4; i += stride) {
        float4 P0 = bp[i], T0 = bt[i], Y0 = sp[i], Z0 = st[i];
        float bsum = 0.f, dsum = 0.f;
        loss_elem(P0.x, T0.x, Y0.x, Z0.x, bsum, dsum);
        loss_elem(P0.y, T0.y, Y0.y, Z0.y, bsum, dsum);
        loss_elem(P0.z, T0.z, Y0.z, Z0.z, bsum, dsum);
        loss_elem(P0.w, T0.w, Y0.w, Z0.w, bsum, dsum);
        abce += (double)bsum;
        adur += (double)dsum;
    }
    const int rem = n - (n4 << 2);   // defensive; zero for this shape
    if (rem && blockIdx.x == 0 && threadIdx.x == 0) {
        float bsum = 0.f, dsum = 0.f;
        for (int k = n4 << 2; k < n; ++k)
            loss_elem(bp_s[k], bt_s[k], sp_s[k], st_s[k], bsum, dsum);
        abce += (double)bsum;
        adur += (double)dsum;
    }

    // wave reduce (64 lanes)
    for (int off = 32; off > 0; off >>= 1) {
        abce += __shfl_down(abce, off);
        adur += __shfl_down(adur, off);
    }
    __shared__ double sb[4], sd[4];
    const int lane = threadIdx.x & 63;
    const int wid  = threadIdx.x >> 6;
    if (lane == 0) { sb[wid] = abce; sd[wid] = adur; }
    __syncthreads();
    if (threadIdx.x == 0)
        partials[blockIdx.x] = make_double2(sb[0] + sb[1] + sb[2] + sb[3],
                                            sd[0] + sd[1] + sd[2] + sd[3]);
}

// Pass 2: one block reduces NBLOCKS partial pairs, writes the 3 outputs.
__global__ __launch_bounds__(256) void loss_finalize_kernel(
    const double2* __restrict__ partials, float* __restrict__ out, double invn)
{
    double abce = 0.0, adur = 0.0;
    for (int i = threadIdx.x; i < NBLOCKS; i += 256) {
        double2 v = partials[i];
        abce += v.x;
        adur += v.y;
    }
    for (int off = 32; off > 0; off >>= 1) {
        abce += __shfl_down(abce, off);
        adur += __shfl_down(adur, off);
    }
    __shared__ double sb[4], sd[4];
    const int lane = threadIdx.x & 63;
    const int wid  = threadIdx.x >> 6;
    if (lane == 0) { sb[wid] = abce; sd[wid] = adur; }
    __syncthreads();
    if (threadIdx.x == 0) {
        double bce = (sb[0] + sb[1] + sb[2] + sb[3]) * NEG_LN2 * invn;
        double dur = (sd[0] + sd[1] + sd[2] + sd[3]) * ALPHA_D * invn;
        out[0] = (float)(bce + dur);
        out[1] = (float)bce;
        out[2] = (float)dur;
    }
}

extern "C" void kernel_launch(void* const* d_in, const int* in_sizes, int n_in,
                              void* d_out, int out_size, void* d_ws, size_t ws_size,
                              hipStream_t stream)
{
    const float* bp = (const float*)d_in[0];
    const float* bt = (const float*)d_in[1];
    const float* sp = (const float*)d_in[2];
    const float* st = (const float*)d_in[3];
    float* out = (float*)d_out;
    double2* partials = (double2*)d_ws;     // NBLOCKS * 16 B = 16 KB scratch

    const int n = in_sizes[0];   // 64 * 131072 = 8,388,608

    // Every partial slot is unconditionally overwritten -> no memset needed.
    loss_main_kernel<<<NBLOCKS, 256, 0, stream>>>(bp, bt, sp, st, partials, n);
    loss_finalize_kernel<<<1, 256, 0, stream>>>(partials, out, 1.0 / (double)n);
}